// Round 6
// baseline (72.073 us; speedup 1.0000x reference)
//
#include <hip/hip_runtime.h>
#include <cstdint>

#define B_ 8
#define T_ 2048
#define C_ 1024
#define H_ 64
#define BT_ (B_ * T_)

typedef short short8 __attribute__((ext_vector_type(8)));
typedef float f32x4 __attribute__((ext_vector_type(4)));

__device__ inline short f2bf(float f) {
  uint32_t u = __float_as_uint(f);
  u += 0x7fffu + ((u >> 16) & 1u);  // RNE; inputs finite
  return (short)(u >> 16);
}

// async global->LDS, 16B per lane; LDS dest = uniform base + lane*16 (HW rule)
__device__ __forceinline__ void gl_lds16(const void* g, void* l) {
  __builtin_amdgcn_global_load_lds(
      (const __attribute__((address_space(1))) unsigned int*)g,
      (__attribute__((address_space(3))) unsigned int*)l, 16, 0, 0);
}

// ---------------------------------------------------------------------------
// prep_w: Wk/Wq/Wv [1024][64] fp32 -> Wt [192][1024] bf16 (transposed).
// Folded into Wk: score scale 1024^-0.5 AND log2(e) so attn softmax runs in
// log2 domain (exp2 = 1 VALU op vs __expf's 2). Queries = x@Wk source quirk.
// ---------------------------------------------------------------------------
__global__ __launch_bounds__(256) void prep_w(
    const float* __restrict__ Wk, const float* __restrict__ Wq,
    const float* __restrict__ Wv, short* __restrict__ Wt) {
  __shared__ float wl[64][68];
  const int mat = blockIdx.x >> 4;
  const int kc = blockIdx.x & 15;
  const float* W = (mat == 0) ? Wk : (mat == 1) ? Wq : Wv;
  const float sc = (mat == 0) ? 0.03125f * 1.44269504088896f : 1.0f;
  const int t = threadIdx.x;
  const int k0 = kc * 64;
#pragma unroll
  for (int j = 0; j < 4; ++j) {
    int s = t + 256 * j;
    int kr = s >> 4, cf = s & 15;
    float4 v = *reinterpret_cast<const float4*>(&W[(size_t)(k0 + kr) * H_ + cf * 4]);
    wl[kr][cf * 4 + 0] = v.x; wl[kr][cf * 4 + 1] = v.y;
    wl[kr][cf * 4 + 2] = v.z; wl[kr][cf * 4 + 3] = v.w;
  }
  __syncthreads();
#pragma unroll
  for (int j = 0; j < 2; ++j) {
    int s = t + 256 * j;
    int n = s >> 3, g = s & 7;
    short8 o;
#pragma unroll
    for (int i = 0; i < 8; ++i) o[i] = f2bf(wl[8 * g + i][n] * sc);
    *reinterpret_cast<short8*>(&Wt[(size_t)(mat * 64 + n) * C_ + k0 + 8 * g]) = o;
  }
}

// ---------------------------------------------------------------------------
// proj: m97-style GEMM (unchanged from R5, ~15us). 512 blocks x 128 thr.
// Tile M=32 x N=192, K-step 64, double-buffered LDS via global_load_lds(16B)
// with pre-swizzled global source; XOR-swizzled LDS reads.
// ---------------------------------------------------------------------------
__global__ __launch_bounds__(128, 1) void proj_kernel(
    const float* __restrict__ x, const short* __restrict__ Wt,
    short* __restrict__ Kp, short* __restrict__ Qp, short* __restrict__ Vt) {
  __shared__ float xs[2][32 * 64];   // 8KB each: 32 rows x 16 slots(16B)
  __shared__ short ws[2][192 * 64];  // 24KB each: 192 rows x 8 slots(16B)
  const int t = threadIdx.x;
  const int w = t >> 6, lane = t & 63;
  const int l15 = lane & 15, lg = lane >> 4;
  const int rowBase = blockIdx.x * 32;

  f32x4 acc[12];
  const f32x4 zf = {0.f, 0.f, 0.f, 0.f};
#pragma unroll
  for (int i = 0; i < 12; ++i) acc[i] = zf;

  auto stage = [&](int buf, int k0) {
#pragma unroll
    for (int j = 0; j < 4; ++j) {
      const int seg = w * 4 + j;
      const int r = seg * 4 + (lane >> 4);
      const float* g =
          &x[(size_t)(rowBase + r) * C_ + k0 + (((lane & 15) ^ (r & 7)) << 2)];
      gl_lds16(g, (char*)&xs[buf][0] + seg * 1024);
    }
#pragma unroll
    for (int j = 0; j < 12; ++j) {
      const int seg = w * 12 + j;
      const int n = seg * 8 + (lane >> 3);
      const short* g =
          &Wt[(size_t)n * C_ + k0 + (((lane & 7) ^ (n & 7)) << 3)];
      gl_lds16(g, (char*)&ws[buf][0] + seg * 1024);
    }
  };

  stage(0, 0);

#pragma unroll 1
  for (int it = 0; it < 16; ++it) {
    __syncthreads();
    const int cb = it & 1;
    if (it < 15) stage(cb ^ 1, (it + 1) * 64);
    const int arow = 16 * w + l15;
    const int x7 = arow & 7;
    const float* xrow = &xs[cb][arow * 64];
    float4 fa = *reinterpret_cast<const float4*>(xrow + (((2 * lg) ^ x7) << 2));
    float4 fb = *reinterpret_cast<const float4*>(xrow + (((2 * lg + 1) ^ x7) << 2));
    float4 fc = *reinterpret_cast<const float4*>(xrow + (((2 * lg + 8) ^ x7) << 2));
    float4 fd = *reinterpret_cast<const float4*>(xrow + (((2 * lg + 9) ^ x7) << 2));
    short8 a0, a1;
    a0[0] = f2bf(fa.x); a0[1] = f2bf(fa.y); a0[2] = f2bf(fa.z); a0[3] = f2bf(fa.w);
    a0[4] = f2bf(fb.x); a0[5] = f2bf(fb.y); a0[6] = f2bf(fb.z); a0[7] = f2bf(fb.w);
    a1[0] = f2bf(fc.x); a1[1] = f2bf(fc.y); a1[2] = f2bf(fc.z); a1[3] = f2bf(fc.w);
    a1[4] = f2bf(fd.x); a1[5] = f2bf(fd.y); a1[6] = f2bf(fd.z); a1[7] = f2bf(fd.w);
#pragma unroll
    for (int nt = 0; nt < 12; ++nt) {
      const int n2 = 16 * nt + l15, n7 = n2 & 7;
      const short* wrow = &ws[cb][n2 * 64];
      short8 b0 = *reinterpret_cast<const short8*>(wrow + ((lg ^ n7) << 3));
      short8 b1 = *reinterpret_cast<const short8*>(wrow + (((4 + lg) ^ n7) << 3));
      acc[nt] = __builtin_amdgcn_mfma_f32_16x16x32_bf16(a0, b0, acc[nt], 0, 0, 0);
      acc[nt] = __builtin_amdgcn_mfma_f32_16x16x32_bf16(a1, b1, acc[nt], 0, 0, 0);
    }
  }

  const int strip = blockIdx.x * 2 + w;
  const int rb = strip * 16;
#pragma unroll
  for (int nt = 0; nt < 4; ++nt)
#pragma unroll
    for (int r = 0; r < 4; ++r) {
      const size_t orow = rb + lg * 4 + r;
      Kp[orow * H_ + nt * 16 + l15] = f2bf(acc[nt][r]);
      Qp[orow * H_ + nt * 16 + l15] = f2bf(acc[4 + nt][r]);
    }
  __syncthreads();
  short* vl = reinterpret_cast<short*>(&xs[0][0]) + w * (16 * 66);
#pragma unroll
  for (int nt = 0; nt < 4; ++nt)
#pragma unroll
    for (int r = 0; r < 4; ++r)
      vl[(lg * 4 + r) * 66 + nt * 16 + l15] = f2bf(acc[8 + nt][r]);
  asm volatile("s_waitcnt lgkmcnt(0)" ::: "memory");
  short8 o0, o1;
#pragma unroll
  for (int i = 0; i < 8; ++i) o0[i] = vl[i * 66 + lane];
#pragma unroll
  for (int i = 0; i < 8; ++i) o1[i] = vl[(8 + i) * 66 + lane];
  const int bb = strip >> 7, tb = (strip & 127) * 16;
  short* dst = &Vt[((size_t)bb * H_ + lane) * T_ + tb];
  *reinterpret_cast<short8*>(dst) = o0;
  *reinterpret_cast<short8*>(dst + 8) = o1;
}

// ---------------------------------------------------------------------------
// attn: causal flash attention, bf16 MFMA, flash-decoding k-split x4.
// 1024 blocks (batch x 128 q-tiles, expensive tiles dispatched first) x
// 256 thr (4 waves); wave s handles k-tiles kt = s, s+4, ... of its tile.
// Kc-reuse prefetch: next K-frags load into the same registers right after
// QK^T, overlapping softmax+PV. Softmax in log2 domain (scale pre-folded).
// ---------------------------------------------------------------------------
__global__ __launch_bounds__(256, 2) void attn_kernel(
    const short* __restrict__ Kq, const short* __restrict__ Qk,
    const short* __restrict__ Vt, float* __restrict__ out) {
  __shared__ short Ps[4][16 * 64];
  __shared__ float Po[4][16][68];
  __shared__ float Ml[4][16][2];
  const int t = threadIdx.x, s = t >> 6, lane = t & 63;
  const int l15 = lane & 15, lg = lane >> 4;
  const int batch = blockIdx.x & 7;
  const int u = 127 - (blockIdx.x >> 3);  // large u (most k-tiles) first
  const short* Kb = Kq + (size_t)batch * T_ * H_;
  const short* Qb = Qk + (size_t)batch * T_ * H_;
  const short* Vb = Vt + (size_t)batch * H_ * T_;
  float* ob = out + (size_t)batch * T_ * H_;
  short* ps = &Ps[s][0];
  const f32x4 zf = {0.f, 0.f, 0.f, 0.f};

  const int qbase = u * 16;
  const short* qp = &Kb[(size_t)(qbase + l15) * H_ + lg * 8];
  const short8 qa0 = *reinterpret_cast<const short8*>(qp);
  const short8 qa1 = *reinterpret_cast<const short8*>(qp + 32);
  f32x4 O[4];
  float m[4], l[4];
#pragma unroll
  for (int i = 0; i < 4; ++i) { O[i] = zf; m[i] = -1e30f; l[i] = 0.f; }
  const int nkt = (u >> 2) + 1;
  const int cnt = (s < nkt) ? ((nkt - 1 - s) >> 2) + 1 : 0;
  int kt = s;

  short8 Kc[8];
  if (cnt > 0) {
#pragma unroll
    for (int nt = 0; nt < 4; ++nt) {
      const short* kp = &Qb[(size_t)(kt * 64 + 16 * nt + l15) * H_ + lg * 8];
      Kc[2 * nt]     = *reinterpret_cast<const short8*>(kp);
      Kc[2 * nt + 1] = *reinterpret_cast<const short8*>(kp + 32);
    }
  }
#pragma unroll 1
  for (int i = 0; i < cnt; ++i) {
    const int kbase = kt * 64;
    // V loads for this iter (consumed in PV, ~800cy later)
    short8 Vc[8];
#pragma unroll
    for (int nt = 0; nt < 4; ++nt) {
      const short* vp = &Vb[(size_t)(16 * nt + l15) * T_ + kbase + lg * 8];
      Vc[nt]     = *reinterpret_cast<const short8*>(vp);
      Vc[4 + nt] = *reinterpret_cast<const short8*>(vp + 32);
    }
    // QK^T (S holds score * log2e; scale folded into Kp projection)
    f32x4 S[4];
#pragma unroll
    for (int nt = 0; nt < 4; ++nt) S[nt] = zf;
    __builtin_amdgcn_s_setprio(1);
#pragma unroll
    for (int nt = 0; nt < 4; ++nt) {
      S[nt] = __builtin_amdgcn_mfma_f32_16x16x32_bf16(qa0, Kc[2 * nt], S[nt], 0, 0, 0);
      S[nt] = __builtin_amdgcn_mfma_f32_16x16x32_bf16(qa1, Kc[2 * nt + 1], S[nt], 0, 0, 0);
    }
    __builtin_amdgcn_s_setprio(0);
    const bool last = (kt == nkt - 1);
    const bool more = (i + 1 < cnt);
    // next-iter K prefetch into the SAME registers (QK^T is done with them);
    // overlaps with softmax + PV below.
    if (more) {
#pragma unroll
      for (int nt = 0; nt < 4; ++nt) {
        const short* kp =
            &Qb[(size_t)((kt + 4) * 64 + 16 * nt + l15) * H_ + lg * 8];
        Kc[2 * nt]     = *reinterpret_cast<const short8*>(kp);
        Kc[2 * nt + 1] = *reinterpret_cast<const short8*>(kp + 32);
      }
    }
    float rmax[4];
#pragma unroll
    for (int r = 0; r < 4; ++r) {
      if (last) {
#pragma unroll
        for (int nt = 0; nt < 4; ++nt)
          if (kbase + 16 * nt + l15 > qbase + lg * 4 + r) S[nt][r] = -1e30f;
      }
      float mx = fmaxf(fmaxf(S[0][r], S[1][r]), fmaxf(S[2][r], S[3][r]));
      mx = fmaxf(mx, __shfl_xor(mx, 1));
      mx = fmaxf(mx, __shfl_xor(mx, 2));
      mx = fmaxf(mx, __shfl_xor(mx, 4));
      mx = fmaxf(mx, __shfl_xor(mx, 8));
      rmax[r] = mx;
    }
#pragma unroll
    for (int r = 0; r < 4; ++r) {
      const float mn = fmaxf(m[r], rmax[r]);
      const float sc = exp2f(m[r] - mn);
      m[r] = mn;
      float rs = 0.f;
#pragma unroll
      for (int nt = 0; nt < 4; ++nt) {
        const float p = exp2f(S[nt][r] - mn);
        S[nt][r] = p;
        rs += p;
      }
      rs += __shfl_xor(rs, 1);
      rs += __shfl_xor(rs, 2);
      rs += __shfl_xor(rs, 4);
      rs += __shfl_xor(rs, 8);
      l[r] = l[r] * sc + rs;
#pragma unroll
      for (int nt = 0; nt < 4; ++nt) O[nt][r] *= sc;
      const int row = lg * 4 + r;
#pragma unroll
      for (int nt = 0; nt < 4; ++nt)
        ps[row * 64 + ((16 * nt + l15) ^ ((row & 7) << 3))] = f2bf(S[nt][r]);
    }
    __builtin_amdgcn_s_setprio(1);
#pragma unroll
    for (int kc = 0; kc < 2; ++kc) {
      short8 pa = *reinterpret_cast<const short8*>(
          &ps[l15 * 64 + ((kc * 32 + lg * 8) ^ ((l15 & 7) << 3))]);
#pragma unroll
      for (int nt = 0; nt < 4; ++nt)
        O[nt] = __builtin_amdgcn_mfma_f32_16x16x32_bf16(pa, Vc[kc * 4 + nt], O[nt], 0, 0, 0);
    }
    __builtin_amdgcn_s_setprio(0);
    kt += 4;
  }
  // publish partials (unnormalized O, per-row m/l; m in log2 domain)
#pragma unroll
  for (int nt = 0; nt < 4; ++nt)
#pragma unroll
    for (int r = 0; r < 4; ++r)
      Po[s][lg * 4 + r][nt * 16 + l15] = O[nt][r];
  if (l15 == 0) {
#pragma unroll
    for (int r = 0; r < 4; ++r) {
      Ml[s][lg * 4 + r][0] = m[r];
      Ml[s][lg * 4 + r][1] = l[r];
    }
  }
  __syncthreads();
  // combine 4 partials -> output (thread t: row t>>4, f4-col t&15)
  {
    const int row = t >> 4, c4 = t & 15;
    float M = fmaxf(fmaxf(Ml[0][row][0], Ml[1][row][0]),
                    fmaxf(Ml[2][row][0], Ml[3][row][0]));
    float L = 0.f;
    f32x4 o = zf;
#pragma unroll
    for (int s2 = 0; s2 < 4; ++s2) {
      const float sc = exp2f(Ml[s2][row][0] - M);
      L += Ml[s2][row][1] * sc;
      const f32x4 po = *reinterpret_cast<const f32x4*>(&Po[s2][row][c4 * 4]);
      o += po * sc;
    }
    const f32x4 res = o * (1.f / L);
    *reinterpret_cast<f32x4*>(&ob[(size_t)(qbase + row) * H_ + c4 * 4]) = res;
  }
}

extern "C" void kernel_launch(void* const* d_in, const int* in_sizes, int n_in,
                              void* d_out, int out_size, void* d_ws, size_t ws_size,
                              hipStream_t stream) {
  const float* x = (const float*)d_in[0];
  const float* Wk = (const float*)d_in[1];
  const float* Wq = (const float*)d_in[2];
  const float* Wv = (const float*)d_in[3];
  float* out = (float*)d_out;

  short* Kp = (short*)d_ws;                  // [BT][64] bf16 (queries: x@Wk, scale*log2e folded)
  short* Qp = Kp + (size_t)BT_ * H_;         // [BT][64] bf16 (keys:    x@Wq)
  short* Vt = Qp + (size_t)BT_ * H_;         // [8][64][2048] bf16 (values^T)
  short* Wt = Vt + (size_t)BT_ * H_;         // [192][1024] bf16

  hipLaunchKernelGGL(prep_w, dim3(48), dim3(256), 0, stream, Wk, Wq, Wv, Wt);
  hipLaunchKernelGGL(proj_kernel, dim3(512), dim3(128), 0, stream, x, Wt, Kp, Qp, Vt);
  hipLaunchKernelGGL(attn_kernel, dim3(1024), dim3(256), 0, stream, Kp, Qp, Vt, out);
}

// Round 7
// 71.541 us; speedup vs baseline: 1.0074x; 1.0074x over previous
//
#include <hip/hip_runtime.h>
#include <cstdint>

#define B_ 8
#define T_ 2048
#define C_ 1024
#define H_ 64
#define BT_ (B_ * T_)

typedef short short8 __attribute__((ext_vector_type(8)));
typedef short bh4 __attribute__((ext_vector_type(4)));
typedef float f32x4 __attribute__((ext_vector_type(4)));

__device__ inline short f2bf(float f) {
  uint32_t u = __float_as_uint(f);
  u += 0x7fffu + ((u >> 16) & 1u);  // RNE; inputs finite
  return (short)(u >> 16);
}

// async global->LDS, 16B per lane; LDS dest = uniform base + lane*16 (HW rule)
__device__ __forceinline__ void gl_lds16(const void* g, void* l) {
  __builtin_amdgcn_global_load_lds(
      (const __attribute__((address_space(1))) unsigned int*)g,
      (__attribute__((address_space(3))) unsigned int*)l, 16, 0, 0);
}

// ---------------------------------------------------------------------------
// prep_w: Wk/Wq/Wv [1024][64] fp32 -> Wt [192][1024] bf16 (transposed).
// Folded into Wk: score scale 1024^-0.5 AND log2(e) (softmax in log2 domain).
// ---------------------------------------------------------------------------
__global__ __launch_bounds__(256) void prep_w(
    const float* __restrict__ Wk, const float* __restrict__ Wq,
    const float* __restrict__ Wv, short* __restrict__ Wt) {
  __shared__ float wl[64][68];
  const int mat = blockIdx.x >> 4;
  const int kc = blockIdx.x & 15;
  const float* W = (mat == 0) ? Wk : (mat == 1) ? Wq : Wv;
  const float sc = (mat == 0) ? 0.03125f * 1.44269504088896f : 1.0f;
  const int t = threadIdx.x;
  const int k0 = kc * 64;
#pragma unroll
  for (int j = 0; j < 4; ++j) {
    int s = t + 256 * j;
    int kr = s >> 4, cf = s & 15;
    float4 v = *reinterpret_cast<const float4*>(&W[(size_t)(k0 + kr) * H_ + cf * 4]);
    wl[kr][cf * 4 + 0] = v.x; wl[kr][cf * 4 + 1] = v.y;
    wl[kr][cf * 4 + 2] = v.z; wl[kr][cf * 4 + 3] = v.w;
  }
  __syncthreads();
#pragma unroll
  for (int j = 0; j < 2; ++j) {
    int s = t + 256 * j;
    int n = s >> 3, g = s & 7;
    short8 o;
#pragma unroll
    for (int i = 0; i < 8; ++i) o[i] = f2bf(wl[8 * g + i][n] * sc);
    *reinterpret_cast<short8*>(&Wt[(size_t)(mat * 64 + n) * C_ + k0 + 8 * g]) = o;
  }
}

// ---------------------------------------------------------------------------
// proj: m97-style GEMM (unchanged, ~15us). 512 blocks x 128 thr.
// ---------------------------------------------------------------------------
__global__ __launch_bounds__(128, 1) void proj_kernel(
    const float* __restrict__ x, const short* __restrict__ Wt,
    short* __restrict__ Kp, short* __restrict__ Qp, short* __restrict__ Vt) {
  __shared__ float xs[2][32 * 64];
  __shared__ short ws[2][192 * 64];
  const int t = threadIdx.x;
  const int w = t >> 6, lane = t & 63;
  const int l15 = lane & 15, lg = lane >> 4;
  const int rowBase = blockIdx.x * 32;

  f32x4 acc[12];
  const f32x4 zf = {0.f, 0.f, 0.f, 0.f};
#pragma unroll
  for (int i = 0; i < 12; ++i) acc[i] = zf;

  auto stage = [&](int buf, int k0) {
#pragma unroll
    for (int j = 0; j < 4; ++j) {
      const int seg = w * 4 + j;
      const int r = seg * 4 + (lane >> 4);
      const float* g =
          &x[(size_t)(rowBase + r) * C_ + k0 + (((lane & 15) ^ (r & 7)) << 2)];
      gl_lds16(g, (char*)&xs[buf][0] + seg * 1024);
    }
#pragma unroll
    for (int j = 0; j < 12; ++j) {
      const int seg = w * 12 + j;
      const int n = seg * 8 + (lane >> 3);
      const short* g =
          &Wt[(size_t)n * C_ + k0 + (((lane & 7) ^ (n & 7)) << 3)];
      gl_lds16(g, (char*)&ws[buf][0] + seg * 1024);
    }
  };

  stage(0, 0);

#pragma unroll 1
  for (int it = 0; it < 16; ++it) {
    __syncthreads();
    const int cb = it & 1;
    if (it < 15) stage(cb ^ 1, (it + 1) * 64);
    const int arow = 16 * w + l15;
    const int x7 = arow & 7;
    const float* xrow = &xs[cb][arow * 64];
    float4 fa = *reinterpret_cast<const float4*>(xrow + (((2 * lg) ^ x7) << 2));
    float4 fb = *reinterpret_cast<const float4*>(xrow + (((2 * lg + 1) ^ x7) << 2));
    float4 fc = *reinterpret_cast<const float4*>(xrow + (((2 * lg + 8) ^ x7) << 2));
    float4 fd = *reinterpret_cast<const float4*>(xrow + (((2 * lg + 9) ^ x7) << 2));
    short8 a0, a1;
    a0[0] = f2bf(fa.x); a0[1] = f2bf(fa.y); a0[2] = f2bf(fa.z); a0[3] = f2bf(fa.w);
    a0[4] = f2bf(fb.x); a0[5] = f2bf(fb.y); a0[6] = f2bf(fb.z); a0[7] = f2bf(fb.w);
    a1[0] = f2bf(fc.x); a1[1] = f2bf(fc.y); a1[2] = f2bf(fc.z); a1[3] = f2bf(fc.w);
    a1[4] = f2bf(fd.x); a1[5] = f2bf(fd.y); a1[6] = f2bf(fd.z); a1[7] = f2bf(fd.w);
#pragma unroll
    for (int nt = 0; nt < 12; ++nt) {
      const int n2 = 16 * nt + l15, n7 = n2 & 7;
      const short* wrow = &ws[cb][n2 * 64];
      short8 b0 = *reinterpret_cast<const short8*>(wrow + ((lg ^ n7) << 3));
      short8 b1 = *reinterpret_cast<const short8*>(wrow + (((4 + lg) ^ n7) << 3));
      acc[nt] = __builtin_amdgcn_mfma_f32_16x16x32_bf16(a0, b0, acc[nt], 0, 0, 0);
      acc[nt] = __builtin_amdgcn_mfma_f32_16x16x32_bf16(a1, b1, acc[nt], 0, 0, 0);
    }
  }

  const int strip = blockIdx.x * 2 + w;
  const int rb = strip * 16;
#pragma unroll
  for (int nt = 0; nt < 4; ++nt)
#pragma unroll
    for (int r = 0; r < 4; ++r) {
      const size_t orow = rb + lg * 4 + r;
      Kp[orow * H_ + nt * 16 + l15] = f2bf(acc[nt][r]);
      Qp[orow * H_ + nt * 16 + l15] = f2bf(acc[4 + nt][r]);
    }
  __syncthreads();
  short* vl = reinterpret_cast<short*>(&xs[0][0]) + w * (16 * 66);
#pragma unroll
  for (int nt = 0; nt < 4; ++nt)
#pragma unroll
    for (int r = 0; r < 4; ++r)
      vl[(lg * 4 + r) * 66 + nt * 16 + l15] = f2bf(acc[8 + nt][r]);
  asm volatile("s_waitcnt lgkmcnt(0)" ::: "memory");
  short8 o0, o1;
#pragma unroll
  for (int i = 0; i < 8; ++i) o0[i] = vl[i * 66 + lane];
#pragma unroll
  for (int i = 0; i < 8; ++i) o1[i] = vl[(8 + i) * 66 + lane];
  const int bb = strip >> 7, tb = (strip & 127) * 16;
  short* dst = &Vt[((size_t)bb * H_ + lane) * T_ + tb];
  *reinterpret_cast<short8*>(dst) = o0;
  *reinterpret_cast<short8*>(dst + 8) = o1;
}

// ---------------------------------------------------------------------------
// attn: causal flash attention, SWAPPED-OPERAND bf16 MFMA (S^T = K x Q^T):
// each lane owns one q-row (q = lane&15) -> softmax max/sum are in-lane trees
// + 2 shfl_xor(16/32); m,l are per-lane scalars. PV computes O^T = V^T x P^T
// (Vt is exactly the A-operand). 1024 blocks x 256 thr, k-split x4,
// Kc prefetch pinned above softmax via sched_barrier(0). Log2-domain softmax.
// ---------------------------------------------------------------------------
__global__ __launch_bounds__(256, 2) void attn_kernel(
    const short* __restrict__ Kq, const short* __restrict__ Qk,
    const short* __restrict__ Vt, float* __restrict__ out) {
  __shared__ short Ps[4][16 * 64];
  __shared__ float Po[4][16][68];
  __shared__ float Ml[4][16][2];
  const int t = threadIdx.x, s = t >> 6, lane = t & 63;
  const int l15 = lane & 15, lg = lane >> 4;
  const int batch = blockIdx.x & 7;     // consecutive blocks -> different XCDs,
  const int u = 127 - (blockIdx.x >> 3);  // each XCD sees ~1 batch (L2 affinity)
  const short* Kb = Kq + (size_t)batch * T_ * H_;
  const short* Qb = Qk + (size_t)batch * T_ * H_;
  const short* Vb = Vt + (size_t)batch * H_ * T_;
  float* ob = out + (size_t)batch * T_ * H_;
  short* ps = &Ps[s][0];
  const f32x4 zf = {0.f, 0.f, 0.f, 0.f};
  const int m7 = (l15 & 7) << 3;

  const int qbase = u * 16;
  // query fragments (B-operand): col = q = l15, k = lg*8+j
  const short* qp = &Kb[(size_t)(qbase + l15) * H_ + lg * 8];
  const short8 qa0 = *reinterpret_cast<const short8*>(qp);
  const short8 qa1 = *reinterpret_cast<const short8*>(qp + 32);
  f32x4 O[4];  // O^T: lane q=l15 holds d = 16nt + 4lg + r
#pragma unroll
  for (int i = 0; i < 4; ++i) O[i] = zf;
  float m = -1e30f, l = 0.f;
  const int nkt = (u >> 2) + 1;
  const int cnt = (s < nkt) ? ((nkt - 1 - s) >> 2) + 1 : 0;
  int kt = s;

  short8 Kc[8];  // key fragments (A-operand): row = key = l15, k = lg*8+j
  if (cnt > 0) {
#pragma unroll
    for (int nt = 0; nt < 4; ++nt) {
      const short* kp = &Qb[(size_t)(kt * 64 + 16 * nt + l15) * H_ + lg * 8];
      Kc[2 * nt]     = *reinterpret_cast<const short8*>(kp);
      Kc[2 * nt + 1] = *reinterpret_cast<const short8*>(kp + 32);
    }
  }
#pragma unroll 1
  for (int i = 0; i < cnt; ++i) {
    const int kbase = kt * 64;
    // V^T fragments (A-operand for PV): row = d = 16nt+l15, k within chunk
    short8 Vc[8];
#pragma unroll
    for (int nt = 0; nt < 4; ++nt) {
      const short* vp = &Vb[(size_t)(16 * nt + l15) * T_ + kbase + lg * 8];
      Vc[nt]     = *reinterpret_cast<const short8*>(vp);       // kc = 0
      Vc[4 + nt] = *reinterpret_cast<const short8*>(vp + 32);  // kc = 1
    }
    // QK^T swapped: S^T[k][q]; lane l15=q holds k = 16nt + 4lg + r
    f32x4 S[4];
#pragma unroll
    for (int nt = 0; nt < 4; ++nt) S[nt] = zf;
    __builtin_amdgcn_s_setprio(1);
#pragma unroll
    for (int nt = 0; nt < 4; ++nt) {
      S[nt] = __builtin_amdgcn_mfma_f32_16x16x32_bf16(Kc[2 * nt], qa0, S[nt], 0, 0, 0);
      S[nt] = __builtin_amdgcn_mfma_f32_16x16x32_bf16(Kc[2 * nt + 1], qa1, S[nt], 0, 0, 0);
    }
    __builtin_amdgcn_s_setprio(0);
    const bool last = (kt == nkt - 1);
    const bool more = (i + 1 < cnt);
    // next-iter key prefetch (old Kc dead after QK^T); pinned by sched_barrier
    if (more) {
#pragma unroll
      for (int nt = 0; nt < 4; ++nt) {
        const short* kp =
            &Qb[(size_t)((kt + 4) * 64 + 16 * nt + l15) * H_ + lg * 8];
        Kc[2 * nt]     = *reinterpret_cast<const short8*>(kp);
        Kc[2 * nt + 1] = *reinterpret_cast<const short8*>(kp + 32);
      }
    }
    __builtin_amdgcn_sched_barrier(0);
    // causal mask: key k > query q
    if (last) {
#pragma unroll
      for (int nt = 0; nt < 4; ++nt) {
        const int klo = kbase + 16 * nt + 4 * lg;
#pragma unroll
        for (int r = 0; r < 4; ++r)
          if (klo + r > qbase + l15) S[nt][r] = -1e30f;
      }
    }
    // row max: in-lane tree over 16 + 2 shfl
    float mx0 = fmaxf(fmaxf(S[0][0], S[0][1]), fmaxf(S[0][2], S[0][3]));
    float mx1 = fmaxf(fmaxf(S[1][0], S[1][1]), fmaxf(S[1][2], S[1][3]));
    float mx2 = fmaxf(fmaxf(S[2][0], S[2][1]), fmaxf(S[2][2], S[2][3]));
    float mx3 = fmaxf(fmaxf(S[3][0], S[3][1]), fmaxf(S[3][2], S[3][3]));
    float mx = fmaxf(fmaxf(mx0, mx1), fmaxf(mx2, mx3));
    mx = fmaxf(mx, __shfl_xor(mx, 16));
    mx = fmaxf(mx, __shfl_xor(mx, 32));
    const float mn = fmaxf(m, mx);
    const float sc = exp2f(m - mn);
    m = mn;
    // exp + row sum (in-lane tree + 2 shfl)
    float rs = 0.f;
#pragma unroll
    for (int nt = 0; nt < 4; ++nt) {
#pragma unroll
      for (int r = 0; r < 4; ++r) {
        const float p = exp2f(S[nt][r] - mn);
        S[nt][r] = p;
        rs += p;
      }
    }
    rs += __shfl_xor(rs, 16);
    rs += __shfl_xor(rs, 32);
    l = l * sc + rs;
#pragma unroll
    for (int nt = 0; nt < 4; ++nt) O[nt] *= sc;
    // P^T -> LDS as [q=l15][k], XOR-swizzled (proven 0-conflict pattern)
#pragma unroll
    for (int nt = 0; nt < 4; ++nt) {
      bh4 pk;
      pk[0] = f2bf(S[nt][0]); pk[1] = f2bf(S[nt][1]);
      pk[2] = f2bf(S[nt][2]); pk[3] = f2bf(S[nt][3]);
      *reinterpret_cast<bh4*>(&ps[l15 * 64 + ((16 * nt + 4 * lg) ^ m7)]) = pk;
    }
    // PV: O^T += V^T x P^T
    __builtin_amdgcn_s_setprio(1);
#pragma unroll
    for (int kc = 0; kc < 2; ++kc) {
      const short8 pa = *reinterpret_cast<const short8*>(
          &ps[l15 * 64 + ((32 * kc + 8 * lg) ^ m7)]);
#pragma unroll
      for (int nt = 0; nt < 4; ++nt)
        O[nt] = __builtin_amdgcn_mfma_f32_16x16x32_bf16(Vc[kc * 4 + nt], pa, O[nt], 0, 0, 0);
    }
    __builtin_amdgcn_s_setprio(0);
    kt += 4;
  }
  // publish partials: Po[s][q][d] (O^T lane layout: d = 16nt+4lg+r consecutive)
#pragma unroll
  for (int nt = 0; nt < 4; ++nt)
    *reinterpret_cast<f32x4*>(&Po[s][l15][16 * nt + 4 * lg]) = O[nt];
  if (lane < 16) {
    Ml[s][l15][0] = m;
    Ml[s][l15][1] = l;
  }
  __syncthreads();
  // combine 4 partials -> output (thread t: row t>>4, f4-col t&15)
  {
    const int row = t >> 4, c4 = t & 15;
    float M = fmaxf(fmaxf(Ml[0][row][0], Ml[1][row][0]),
                    fmaxf(Ml[2][row][0], Ml[3][row][0]));
    float L = 0.f;
    f32x4 o = zf;
#pragma unroll
    for (int s2 = 0; s2 < 4; ++s2) {
      const float sc = exp2f(Ml[s2][row][0] - M);
      L += Ml[s2][row][1] * sc;
      const f32x4 po = *reinterpret_cast<const f32x4*>(&Po[s2][row][c4 * 4]);
      o += po * sc;
    }
    const f32x4 res = o * (1.f / L);
    *reinterpret_cast<f32x4*>(&ob[(size_t)(qbase + row) * H_ + c4 * 4]) = res;
  }
}

extern "C" void kernel_launch(void* const* d_in, const int* in_sizes, int n_in,
                              void* d_out, int out_size, void* d_ws, size_t ws_size,
                              hipStream_t stream) {
  const float* x = (const float*)d_in[0];
  const float* Wk = (const float*)d_in[1];
  const float* Wq = (const float*)d_in[2];
  const float* Wv = (const float*)d_in[3];
  float* out = (float*)d_out;

  short* Kp = (short*)d_ws;                  // [BT][64] bf16 (queries: x@Wk, scale*log2e folded)
  short* Qp = Kp + (size_t)BT_ * H_;         // [BT][64] bf16 (keys:    x@Wq)
  short* Vt = Qp + (size_t)BT_ * H_;         // [8][64][2048] bf16 (values^T)
  short* Wt = Vt + (size_t)BT_ * H_;         // [192][1024] bf16

  hipLaunchKernelGGL(prep_w, dim3(48), dim3(256), 0, stream, Wk, Wq, Wv, Wt);
  hipLaunchKernelGGL(proj_kernel, dim3(512), dim3(128), 0, stream, x, Wt, Kp, Qp, Vt);
  hipLaunchKernelGGL(attn_kernel, dim3(1024), dim3(256), 0, stream, Kp, Qp, Vt, out);
}